// Round 8
// baseline (552.561 us; speedup 1.0000x reference)
//
#include <hip/hip_runtime.h>
#include <cstdint>
#include <cstddef>

#define NNODES 100000
#define NEDGES 1600000
#define DIM 128
#define NREL 8
#define NSEG (NNODES * NREL)                       // 800,000 segments
#define SCAN_BLK 2048
#define NSCAN ((NSEG + SCAN_BLK - 1) / SCAN_BLK)   // 391 scan blocks
#define NKT 36                                     // 1152 / 32 K-steps
#define A16ROW 1160                                // f16 LDS row stride (ushorts)
#define CVT4 (NNODES * DIM / 4)                    // 3,200,000 float4 groups
#define NBUCK ((NEDGES + 255) / 256)               // 6250 bucket blocks
#define NPACK (NKT * 8 * 2 / 4)                    // 144 fused pack blocks (256 thr)

typedef float f32x4 __attribute__((ext_vector_type(4)));
typedef short short8 __attribute__((ext_vector_type(8)));
typedef _Float16 half8 __attribute__((ext_vector_type(8)));

__device__ inline float h2f(unsigned short u) {
    return (float)__builtin_bit_cast(_Float16, u);
}
__device__ inline unsigned short f2h(float f) {
    return __builtin_bit_cast(unsigned short, (_Float16)f);
}
__device__ inline half8 hzero() {
    half8 z = {(_Float16)0, (_Float16)0, (_Float16)0, (_Float16)0,
               (_Float16)0, (_Float16)0, (_Float16)0, (_Float16)0};
    return z;
}

// ------------------------------------------------- count + cvt (fused) ----
// NOTE: grid must cover max(NEDGES, CVT4) threads; both parts are guarded.
__global__ __launch_bounds__(256) void count_cvt(const int* __restrict__ dst,
                                                 const int* __restrict__ et,
                                                 int* __restrict__ cnt,
                                                 const float* __restrict__ x,
                                                 unsigned short* __restrict__ xh) {
    int gid = blockIdx.x * 256 + threadIdx.x;
    if (gid < NEDGES) atomicAdd(&cnt[dst[gid] * NREL + et[gid]], 1);
    if (gid < CVT4) {
        float4 v = *(const float4*)(x + (size_t)gid * 4);
        ushort4 o = make_ushort4(f2h(v.x), f2h(v.y), f2h(v.z), f2h(v.w));
        *(ushort4*)(xh + (size_t)gid * 4) = o;
    }
}

// ------------------------------------------------- scan pass1 (+inv fuse) ---
// NOTE: two-kernel scan on purpose — a single-kernel "last block scans"
// variant (round 7) raced intermittently under graph replay (cross-XCD
// visibility); the kernel boundary is the safe device-wide barrier.
__global__ __launch_bounds__(256) void scan_pass1(const int* __restrict__ cnt,
                                                  int* __restrict__ bsum,
                                                  float* __restrict__ inv) {
    int base = blockIdx.x * SCAN_BLK + threadIdx.x * 8;
    int s = 0;
#pragma unroll
    for (int j = 0; j < 8; ++j) {
        int i = base + j;
        if (i < NSEG) {
            int c = cnt[i];
            s += c;
            inv[i] = 1.0f / (float)(c > 1 ? c : 1);
        }
    }
    __shared__ int ws[4];
    for (int d = 1; d < 64; d <<= 1) s += __shfl_xor(s, d);
    int lane = threadIdx.x & 63, w = threadIdx.x >> 6;
    if (lane == 0) ws[w] = s;
    __syncthreads();
    if (threadIdx.x == 0) bsum[blockIdx.x] = ws[0] + ws[1] + ws[2] + ws[3];
}

__global__ __launch_bounds__(64) void scan_pass2(int* __restrict__ bsum) {
    int lane = threadIdx.x;
    int vals[7];
    int s = 0;
#pragma unroll
    for (int j = 0; j < 7; ++j) {
        int i = lane * 7 + j;
        vals[j] = (i < NSCAN) ? bsum[i] : 0;
        s += vals[j];
    }
    int incl = s;
    for (int d = 1; d < 64; d <<= 1) {
        int u = __shfl_up(incl, d);
        if (lane >= d) incl += u;
    }
    int base = incl - s;
#pragma unroll
    for (int j = 0; j < 7; ++j) {
        int i = lane * 7 + j;
        if (i < NSCAN) bsum[i] = base;
        base += vals[j];
    }
}

__global__ __launch_bounds__(256) void scan_pass3(const int* __restrict__ cnt,
                                                  const int* __restrict__ bsum,
                                                  int* __restrict__ segend) {
    int tid = threadIdx.x;
    int base = blockIdx.x * SCAN_BLK + tid * 8;
    int v[8];
    int s = 0;
#pragma unroll
    for (int j = 0; j < 8; ++j) {
        int i = base + j;
        v[j] = (i < NSEG) ? cnt[i] : 0;
        s += v[j];
    }
    int lane = tid & 63, w = tid >> 6;
    int incl = s;
    for (int d = 1; d < 64; d <<= 1) {
        int u = __shfl_up(incl, d);
        if (lane >= d) incl += u;
    }
    __shared__ int wtot[4];
    if (lane == 63) wtot[w] = incl;
    __syncthreads();
    int wbase = 0;
#pragma unroll
    for (int k = 0; k < 4; ++k)
        if (k < w) wbase += wtot[k];
    int tbase = bsum[blockIdx.x] + wbase + (incl - s);
#pragma unroll
    for (int j = 0; j < 8; ++j) {
        int i = base + j;
        if (i < NSEG) segend[i] = tbase;   // becomes segment END after bucketing
        tbase += v[j];
    }
}

// ------------------------------------------- bucket + pack_w (fused) -------
// Blocks [0, NBUCK): bucket. Blocks [NBUCK, NBUCK+NPACK): pack both layers'
// W into MFMA B-fragment order. Both parts guarded; grid = sum (disjoint).
// einfo[p] = { src | (rel << 20), f16(inv) duplicated into both halves }.
__global__ __launch_bounds__(256) void bucket_pack(
    const int* __restrict__ src, const int* __restrict__ dst,
    const int* __restrict__ et, const float* __restrict__ inv,
    int* __restrict__ segend, int2* __restrict__ einfo,
    const float* __restrict__ Wrel1, const float* __restrict__ Wroot1,
    const float* __restrict__ Wrel2, const float* __restrict__ Wroot2,
    unsigned short* __restrict__ Wp1, unsigned short* __restrict__ Wp2) {
    if (blockIdx.x < NBUCK) {
        int e = blockIdx.x * 256 + threadIdx.x;
        if (e >= NEDGES) return;
        int seg = dst[e] * NREL + et[e];
        int p = atomicAdd(&segend[seg], 1);
        unsigned ush = f2h(inv[seg]);
        einfo[p] = make_int2(src[e] | ((seg & 7) << 20),
                             (int)(ush | (ush << 16)));
        return;
    }
    // ---- pack part: 4 virtual 64-thread blocks per 256-thread block ----
    int bb = (blockIdx.x - NBUCK) * 4 + (threadIdx.x >> 6);   // 0..575
    const int lane = threadIdx.x & 63;
    const float* Wrel = Wrel1;
    const float* Wroot = Wroot1;
    unsigned short* Wp = Wp1;
    if (bb >= NKT * 8) {
        bb -= NKT * 8;
        Wrel = Wrel2; Wroot = Wroot2; Wp = Wp2;
    }
    const int kt = bb >> 3, ht = bb & 7;
    const int col = ht * 16 + (lane & 15);
    const int kbase = kt * 32 + (lane >> 4) * 8;
    unsigned short vals[8];
#pragma unroll
    for (int j = 0; j < 8; ++j) {
        int k = kbase + j;
        float f = (k < 1024) ? Wrel[(size_t)k * 128 + col]
                             : Wroot[(size_t)(k - 1024) * 128 + col];
        vals[j] = f2h(f);
    }
    unsigned short* dstp = Wp + ((size_t)bb * 64 + lane) * 8;
#pragma unroll
    for (int j = 0; j < 8; ++j) dstp[j] = vals[j];
}

// ---------------------------------------------------------- fused layer ----
// 16 nodes/block, 256 threads, 16 lanes/node.
// Phase 1: double-buffered CSR gather (features for chunk k+1 in flight
//          through compute of chunk k); f16 pk_fma accumulation with scale
//          pre-folded (OOB edges get scale=0 -> no inner guard).
// Phase 2: 4 waves x 2 h-tiles, 36 K-steps mfma_f32_16x16x32_f16.
// Head mode (ow != null): fold h2 @ out_w + sigmoid into the epilogue.
__global__ __launch_bounds__(256, 4) void fused_layer(
    const unsigned short* __restrict__ feat,   // f16 [N][128]
    const int* __restrict__ segend,
    const int2* __restrict__ einfo,
    const unsigned short* __restrict__ Wp,     // packed f16 B-frags
    const float* __restrict__ bias,
    unsigned short* __restrict__ out,          // f16 [N][128] (non-head mode)
    const float* __restrict__ ow,              // head weights or nullptr
    const float* __restrict__ ob,
    float* __restrict__ head_out) {
    __shared__ __align__(16) unsigned short A16[16 * A16ROW + 8];
    const int tid = threadIdx.x;
    const int blk = blockIdx.x;
    const int g = tid >> 4, l16 = tid & 15;

    // ---- phase 0: zero tile ----
    {
        int4* z = (int4*)A16;
        for (int i = tid; i < (16 * A16ROW) / 8; i += 256)
            z[i] = make_int4(0, 0, 0, 0);
    }
    __syncthreads();
    // root rows (disjoint 16B slices)
    *(short8*)(&A16[g * A16ROW + 1024 + l16 * 8]) =
        *(const short8*)(feat + ((size_t)blk * 16 + g) * DIM + l16 * 8);

    // ---- phase 1: double-buffered pipelined gather ----
    {
        const int n = blk * 16 + g;
        const int segbase = n * NREL;
        const int beg = (segbase == 0) ? 0 : segend[segbase - 1];
        const int end = segend[segbase + 7];
        unsigned short* Arow = &A16[g * A16ROW];

        if (beg < end) {
            const int last = end - 1;
            int2 q0[8], q1[8];
            short8 v0[8], v1[8];
            half8 acc = hzero();
            int cur;

            auto loadq = [&](int2* qq, int base) {
#pragma unroll
                for (int u = 0; u < 8; ++u) {
                    int p = base + u;
                    qq[u] = einfo[p < last ? p : last];
                    if (p > last) qq[u].y = 0;     // scale=0 -> no contribution
                }
            };
            auto loadv = [&](short8* vv, const int2* qq) {
#pragma unroll
                for (int u = 0; u < 8; ++u) {
                    const int s = qq[u].x & 0xFFFFF;
                    vv[u] = *(const short8*)(feat + (size_t)s * DIM + l16 * 8);
                }
            };
            auto chunk = [&](const int2* qq, const short8* vv) {
#pragma unroll
                for (int u = 0; u < 8; ++u) {
                    const int rel = ((unsigned)qq[u].x) >> 20;
                    if (rel != cur) {
                        *(short8*)(Arow + cur * DIM + l16 * 8) =
                            __builtin_bit_cast(short8, acc);
                        acc = hzero();
                        cur = rel;
                    }
                    const int y = qq[u].y;
                    int4 t = make_int4(y, y, y, y);
                    half8 scv = __builtin_bit_cast(half8, t);
                    acc += __builtin_bit_cast(half8, vv[u]) * scv;
                }
            };

            loadq(q0, beg);
            loadv(v0, q0);               // chunk 0 features in flight
            loadq(q1, beg + 8);          // chunk 1 einfo in flight
            cur = ((unsigned)q0[0].x) >> 20;

            for (int e = beg; e < end; e += 16) {
                loadv(v1, q1);           // chunk k+1 features (einfo ready)
                chunk(q0, v0);           // compute chunk k (v0 long in flight)
                loadq(q0, e + 16);       // einfo chunk k+2
                if (e + 8 < end) {
                    loadv(v0, q0);       // chunk k+2 features
                    chunk(q1, v1);       // compute chunk k+1
                    loadq(q1, e + 24);   // einfo chunk k+3
                }
            }
            *(short8*)(Arow + cur * DIM + l16 * 8) =
                __builtin_bit_cast(short8, acc);
        }
    }
    __syncthreads();

    // ---- phase 2: MFMA ----
    const int lane = tid & 63;
    const int w = tid >> 6;                 // wave id -> h-tiles 2w, 2w+1
    const int m = lane & 15, kq = lane >> 4;
    const unsigned short* arow = &A16[m * A16ROW + kq * 8];
    f32x4 acc0 = {0.f, 0.f, 0.f, 0.f};
    f32x4 acc1 = {0.f, 0.f, 0.f, 0.f};

#pragma unroll 4
    for (int kt = 0; kt < NKT; ++kt) {
        short8 a = *(const short8*)(arow + kt * 32);
        short8 b0 = *(const short8*)(Wp + ((size_t)(kt * 8 + 2 * w) * 64 + lane) * 8);
        short8 b1 = *(const short8*)(Wp + ((size_t)(kt * 8 + 2 * w + 1) * 64 + lane) * 8);
        acc0 = __builtin_amdgcn_mfma_f32_16x16x32_f16(
            __builtin_bit_cast(half8, a), __builtin_bit_cast(half8, b0), acc0, 0, 0, 0);
        acc1 = __builtin_amdgcn_mfma_f32_16x16x32_f16(
            __builtin_bit_cast(half8, a), __builtin_bit_cast(half8, b1), acc1, 0, 0, 0);
    }

    // ---- epilogue (C/D: col=lane&15, row=(lane>>4)*4+r) ----
    const int col = lane & 15;
    const int rbase = (lane >> 4) * 4;
    const int h0 = 32 * w + col;
    const int h1 = h0 + 16;
    const float bv0 = bias[h0], bv1 = bias[h1];
    float z0[4], z1[4];
#pragma unroll
    for (int r = 0; r < 4; ++r) {
        z0[r] = fmaxf(acc0[r] + bv0, 0.f);
        z1[r] = fmaxf(acc1[r] + bv1, 0.f);
    }
    if (ow == nullptr) {
#pragma unroll
        for (int r = 0; r < 4; ++r) {
            const size_t nrow = ((size_t)blk * 16 + rbase + r) * DIM;
            out[nrow + h0] = f2h(z0[r]);
            out[nrow + h1] = f2h(z1[r]);
        }
    } else {
        // head: per-thread partial dot, LDS reduce, sigmoid
        const float w0 = ow[h0], w1 = ow[h1];
        float pr[4];
#pragma unroll
        for (int r = 0; r < 4; ++r) pr[r] = z0[r] * w0 + z1[r] * w1;
        __syncthreads();                    // A16 ds_reads all complete
        float* P = (float*)A16;             // reuse LDS: [wave][node16][col16]
#pragma unroll
        for (int r = 0; r < 4; ++r)
            P[w * 256 + (rbase + r) * 16 + col] = pr[r];
        __syncthreads();
        const int gg = tid >> 4, ii = tid & 15;
        float s = P[gg * 16 + ii] + P[256 + gg * 16 + ii] +
                  P[512 + gg * 16 + ii] + P[768 + gg * 16 + ii];
        s += __shfl_xor(s, 1);
        s += __shfl_xor(s, 2);
        s += __shfl_xor(s, 4);
        s += __shfl_xor(s, 8);
        if (ii == 0)
            head_out[blk * 16 + gg] = 1.0f / (1.0f + __expf(-(s + ob[0])));
    }
}

// ---------------------------------------------------------------- launch ----
extern "C" void kernel_launch(void* const* d_in, const int* in_sizes, int n_in,
                              void* d_out, int out_size, void* d_ws, size_t ws_size,
                              hipStream_t stream) {
    const float* x      = (const float*)d_in[0];
    const int*   ei     = (const int*)d_in[1];
    const int*   et     = (const int*)d_in[2];
    const float* Wrel1  = (const float*)d_in[3];
    const float* Wroot1 = (const float*)d_in[4];
    const float* b1     = (const float*)d_in[5];
    const float* Wrel2  = (const float*)d_in[6];
    const float* Wroot2 = (const float*)d_in[7];
    const float* b2     = (const float*)d_in[8];
    const float* outw   = (const float*)d_in[9];
    const float* outb   = (const float*)d_in[10];
    const int* src = ei;
    const int* dst = ei + NEDGES;

    // workspace layout (~74 MB, 16B-aligned chunks)
    char* ws = (char*)d_ws;
    int*            cnt     = (int*)(ws + 0);                    //  3,200,000
    int*            bsum    = (int*)(ws + 3200064);              //      4,096
    int*            segend  = (int*)(ws + 3204160);              //  3,200,000
    int2*           einfo   = (int2*)(ws + 6404160);             // 12,800,000
    unsigned short* xh      = (unsigned short*)(ws + 19204160);  // 25,600,000
    unsigned short* h1      = (unsigned short*)(ws + 44804160);  // 25,600,000
    unsigned short* Wp1     = (unsigned short*)(ws + 70404160);  //    294,912
    unsigned short* Wp2     = (unsigned short*)(ws + 70699072);  //    294,912
    float*          inv     = (float*)(ws + 70993984);           //  3,200,000
    // end: 74,193,984 B

    hipMemsetAsync(cnt, 0, (size_t)NSEG * 4, stream);
    // grid sized for the LARGER of the two fused jobs (cvt: 3.2M > edges: 1.6M)
    count_cvt<<<(CVT4 + 255) / 256, 256, 0, stream>>>(dst, et, cnt, x, xh);
    scan_pass1<<<NSCAN, 256, 0, stream>>>(cnt, bsum, inv);
    scan_pass2<<<1, 64, 0, stream>>>(bsum);
    scan_pass3<<<NSCAN, 256, 0, stream>>>(cnt, bsum, segend);
    bucket_pack<<<NBUCK + NPACK, 256, 0, stream>>>(src, dst, et, inv, segend, einfo,
                                                   Wrel1, Wroot1, Wrel2, Wroot2,
                                                   Wp1, Wp2);

    fused_layer<<<NNODES / 16, 256, 0, stream>>>(xh, segend, einfo, Wp1, b1, h1,
                                                 nullptr, nullptr, nullptr);
    fused_layer<<<NNODES / 16, 256, 0, stream>>>(h1, segend, einfo, Wp2, b2, h1,
                                                 outw, outb, (float*)d_out);
}

// Round 11
// 537.975 us; speedup vs baseline: 1.0271x; 1.0271x over previous
//
#include <hip/hip_runtime.h>
#include <cstdint>
#include <cstddef>

#define NNODES 100000
#define NEDGES 1600000
#define DIM 128
#define NREL 8
#define NSEG (NNODES * NREL)                       // 800,000 segments
#define SCAN_BLK 2048
#define NSCAN ((NSEG + SCAN_BLK - 1) / SCAN_BLK)   // 391 scan blocks
#define NKT 36                                     // 1152 / 32 K-steps
#define A16ROW 1160                                // f16 LDS row stride (ushorts)
#define CVT4 (NNODES * DIM / 4)                    // 3,200,000 float4 groups
#define NBUCK ((NEDGES + 255) / 256)               // 6250 bucket blocks
#define NPACK (NKT * 8 * 2 / 4)                    // 144 fused pack blocks (256 thr)

// NOTE (rounds 9/10): a 32-node/512-thread fused_layer with 74 KB static LDS
// killed the MI355X container twice — never validated. Everything here stays
// inside the proven envelope: <=256 threads, <=38 KB LDS.

typedef float f32x4 __attribute__((ext_vector_type(4)));
typedef short short8 __attribute__((ext_vector_type(8)));
typedef _Float16 half8 __attribute__((ext_vector_type(8)));

__device__ inline float h2f(unsigned short u) {
    return (float)__builtin_bit_cast(_Float16, u);
}
__device__ inline unsigned short f2h(float f) {
    return __builtin_bit_cast(unsigned short, (_Float16)f);
}

// ------------------------------------------------- count + cvt (fused) ----
// NOTE: grid must cover max(NEDGES, CVT4) threads; both parts are guarded.
__global__ __launch_bounds__(256) void count_cvt(const int* __restrict__ dst,
                                                 const int* __restrict__ et,
                                                 int* __restrict__ cnt,
                                                 const float* __restrict__ x,
                                                 unsigned short* __restrict__ xh) {
    int gid = blockIdx.x * 256 + threadIdx.x;
    if (gid < NEDGES) atomicAdd(&cnt[dst[gid] * NREL + et[gid]], 1);
    if (gid < CVT4) {
        float4 v = *(const float4*)(x + (size_t)gid * 4);
        ushort4 o = make_ushort4(f2h(v.x), f2h(v.y), f2h(v.z), f2h(v.w));
        *(ushort4*)(xh + (size_t)gid * 4) = o;
    }
}

// ------------------------------------------------- scan pass1 (+inv fuse) ---
// NOTE: two-kernel scan on purpose — a single-kernel "last block scans"
// variant (round 7) raced intermittently under graph replay (cross-XCD
// visibility); the kernel boundary is the safe device-wide barrier.
__global__ __launch_bounds__(256) void scan_pass1(const int* __restrict__ cnt,
                                                  int* __restrict__ bsum,
                                                  float* __restrict__ inv) {
    int base = blockIdx.x * SCAN_BLK + threadIdx.x * 8;
    int s = 0;
#pragma unroll
    for (int j = 0; j < 8; ++j) {
        int i = base + j;
        if (i < NSEG) {
            int c = cnt[i];
            s += c;
            inv[i] = 1.0f / (float)(c > 1 ? c : 1);
        }
    }
    __shared__ int ws[4];
    for (int d = 1; d < 64; d <<= 1) s += __shfl_xor(s, d);
    int lane = threadIdx.x & 63, w = threadIdx.x >> 6;
    if (lane == 0) ws[w] = s;
    __syncthreads();
    if (threadIdx.x == 0) bsum[blockIdx.x] = ws[0] + ws[1] + ws[2] + ws[3];
}

__global__ __launch_bounds__(64) void scan_pass2(int* __restrict__ bsum) {
    int lane = threadIdx.x;
    int vals[7];
    int s = 0;
#pragma unroll
    for (int j = 0; j < 7; ++j) {
        int i = lane * 7 + j;
        vals[j] = (i < NSCAN) ? bsum[i] : 0;
        s += vals[j];
    }
    int incl = s;
    for (int d = 1; d < 64; d <<= 1) {
        int u = __shfl_up(incl, d);
        if (lane >= d) incl += u;
    }
    int base = incl - s;
#pragma unroll
    for (int j = 0; j < 7; ++j) {
        int i = lane * 7 + j;
        if (i < NSCAN) bsum[i] = base;
        base += vals[j];
    }
}

__global__ __launch_bounds__(256) void scan_pass3(const int* __restrict__ cnt,
                                                  const int* __restrict__ bsum,
                                                  int* __restrict__ segend) {
    int tid = threadIdx.x;
    int base = blockIdx.x * SCAN_BLK + tid * 8;
    int v[8];
    int s = 0;
#pragma unroll
    for (int j = 0; j < 8; ++j) {
        int i = base + j;
        v[j] = (i < NSEG) ? cnt[i] : 0;
        s += v[j];
    }
    int lane = tid & 63, w = tid >> 6;
    int incl = s;
    for (int d = 1; d < 64; d <<= 1) {
        int u = __shfl_up(incl, d);
        if (lane >= d) incl += u;
    }
    __shared__ int wtot[4];
    if (lane == 63) wtot[w] = incl;
    __syncthreads();
    int wbase = 0;
#pragma unroll
    for (int k = 0; k < 4; ++k)
        if (k < w) wbase += wtot[k];
    int tbase = bsum[blockIdx.x] + wbase + (incl - s);
#pragma unroll
    for (int j = 0; j < 8; ++j) {
        int i = base + j;
        if (i < NSEG) segend[i] = tbase;   // becomes segment END after bucketing
        tbase += v[j];
    }
}

// ------------------------------------------- bucket + pack_w (fused) -------
// Blocks [0, NBUCK): bucket. Blocks [NBUCK, NBUCK+NPACK): pack both layers'
// W into MFMA B-fragment order. Both parts guarded; grid = sum (disjoint).
// einfo[p] = { src | (rel << 20), f32 bits of inv[seg] }.
__global__ __launch_bounds__(256) void bucket_pack(
    const int* __restrict__ src, const int* __restrict__ dst,
    const int* __restrict__ et, const float* __restrict__ inv,
    int* __restrict__ segend, int2* __restrict__ einfo,
    const float* __restrict__ Wrel1, const float* __restrict__ Wroot1,
    const float* __restrict__ Wrel2, const float* __restrict__ Wroot2,
    unsigned short* __restrict__ Wp1, unsigned short* __restrict__ Wp2) {
    if (blockIdx.x < NBUCK) {
        int e = blockIdx.x * 256 + threadIdx.x;
        if (e >= NEDGES) return;
        int seg = dst[e] * NREL + et[e];
        int p = atomicAdd(&segend[seg], 1);
        einfo[p] = make_int2(src[e] | ((seg & 7) << 20), __float_as_int(inv[seg]));
        return;
    }
    // ---- pack part: 4 virtual 64-thread blocks per 256-thread block ----
    int bb = (blockIdx.x - NBUCK) * 4 + (threadIdx.x >> 6);   // 0..575
    const int lane = threadIdx.x & 63;
    const float* Wrel = Wrel1;
    const float* Wroot = Wroot1;
    unsigned short* Wp = Wp1;
    if (bb >= NKT * 8) {
        bb -= NKT * 8;
        Wrel = Wrel2; Wroot = Wroot2; Wp = Wp2;
    }
    const int kt = bb >> 3, ht = bb & 7;
    const int col = ht * 16 + (lane & 15);
    const int kbase = kt * 32 + (lane >> 4) * 8;
    unsigned short vals[8];
#pragma unroll
    for (int j = 0; j < 8; ++j) {
        int k = kbase + j;
        float f = (k < 1024) ? Wrel[(size_t)k * 128 + col]
                             : Wroot[(size_t)(k - 1024) * 128 + col];
        vals[j] = f2h(f);
    }
    unsigned short* dstp = Wp + ((size_t)bb * 64 + lane) * 8;
#pragma unroll
    for (int j = 0; j < 8; ++j) dstp[j] = vals[j];
}

// ---------------------------------------------------------- fused layer ----
// 16 nodes/block, 256 threads, 16 lanes/node — round-6 proven structure
// (131.9 us): fp32-accum 8-deep prefetch gather, 4 waves x 2 h-tiles MFMA.
// Head mode (ow != null): fold h2 @ out_w + sigmoid into the epilogue
// (proven round 8).
__global__ __launch_bounds__(256, 4) void fused_layer(
    const unsigned short* __restrict__ feat,   // f16 [N][128]
    const int* __restrict__ segend,
    const int2* __restrict__ einfo,
    const unsigned short* __restrict__ Wp,     // packed f16 B-frags
    const float* __restrict__ bias,
    unsigned short* __restrict__ out,          // f16 [N][128] (non-head mode)
    const float* __restrict__ ow,              // head weights or nullptr
    const float* __restrict__ ob,
    float* __restrict__ head_out) {
    __shared__ __align__(16) unsigned short A16[16 * A16ROW + 8];
    const int tid = threadIdx.x;
    const int blk = blockIdx.x;
    const int g = tid >> 4, l16 = tid & 15;

    // ---- phase 0: zero tile ----
    {
        int4* z = (int4*)A16;
        for (int i = tid; i < (16 * A16ROW) / 8; i += 256)
            z[i] = make_int4(0, 0, 0, 0);
    }
    __syncthreads();
    // root rows (disjoint 16B slices)
    *(short8*)(&A16[g * A16ROW + 1024 + l16 * 8]) =
        *(const short8*)(feat + ((size_t)blk * 16 + g) * DIM + l16 * 8);

    // ---- phase 1: pipelined gather (round-6 structure, fp32 accum) ----
    {
        const int n = blk * 16 + g;
        const int segbase = n * NREL;
        const int beg = (segbase == 0) ? 0 : segend[segbase - 1];
        const int end = segend[segbase + 7];
        unsigned short* Arow = &A16[g * A16ROW];

        if (beg < end) {
            const int last = end - 1;
            int2 q[8], qn[8];
            short8 v[8];
#pragma unroll
            for (int u = 0; u < 8; ++u) {
                int p = beg + u;
                q[u] = einfo[p < last ? p : last];
            }
#pragma unroll
            for (int u = 0; u < 8; ++u) {
                const int s = q[u].x & 0xFFFFF;
                v[u] = *(const short8*)(feat + (size_t)s * DIM + l16 * 8);
            }
            float acc[8] = {0.f, 0.f, 0.f, 0.f, 0.f, 0.f, 0.f, 0.f};
            int cur = ((unsigned)q[0].x) >> 20;

            for (int e = beg; e < end; e += 8) {
                // prefetch next einfo chunk
#pragma unroll
                for (int u = 0; u < 8; ++u) {
                    int p = e + 8 + u;
                    qn[u] = einfo[p < last ? p : last];
                }
                // compute current chunk
#pragma unroll
                for (int u = 0; u < 8; ++u) {
                    if (e + u < end) {
                        const int rel = ((unsigned)q[u].x) >> 20;
                        if (rel != cur) {
                            short8 o;
#pragma unroll
                            for (int j = 0; j < 8; ++j) o[j] = (short)f2h(acc[j]);
                            *(short8*)(Arow + cur * DIM + l16 * 8) = o;
#pragma unroll
                            for (int j = 0; j < 8; ++j) acc[j] = 0.f;
                            cur = rel;
                        }
                        const float sc = __int_as_float(q[u].y);
                        const short8 ve = v[u];
#pragma unroll
                        for (int j = 0; j < 8; ++j)
                            acc[j] += h2f((unsigned short)ve[j]) * sc;
                    }
                }
                // issue next chunk's feature gathers (addresses already known)
#pragma unroll
                for (int u = 0; u < 8; ++u) {
                    const int s = qn[u].x & 0xFFFFF;
                    v[u] = *(const short8*)(feat + (size_t)s * DIM + l16 * 8);
                    q[u] = qn[u];
                }
            }
            // final flush
            short8 o;
#pragma unroll
            for (int j = 0; j < 8; ++j) o[j] = (short)f2h(acc[j]);
            *(short8*)(Arow + cur * DIM + l16 * 8) = o;
        }
    }
    __syncthreads();

    // ---- phase 2: MFMA, 4 waves x 2 h-tiles ----
    const int lane = tid & 63;
    const int w = tid >> 6;                 // wave id -> h-tiles 2w, 2w+1
    const int m = lane & 15, kq = lane >> 4;
    const unsigned short* arow = &A16[m * A16ROW + kq * 8];
    f32x4 acc0 = {0.f, 0.f, 0.f, 0.f};
    f32x4 acc1 = {0.f, 0.f, 0.f, 0.f};

#pragma unroll 4
    for (int kt = 0; kt < NKT; ++kt) {
        short8 a = *(const short8*)(arow + kt * 32);
        short8 b0 = *(const short8*)(Wp + ((size_t)(kt * 8 + 2 * w) * 64 + lane) * 8);
        short8 b1 = *(const short8*)(Wp + ((size_t)(kt * 8 + 2 * w + 1) * 64 + lane) * 8);
        acc0 = __builtin_amdgcn_mfma_f32_16x16x32_f16(
            __builtin_bit_cast(half8, a), __builtin_bit_cast(half8, b0), acc0, 0, 0, 0);
        acc1 = __builtin_amdgcn_mfma_f32_16x16x32_f16(
            __builtin_bit_cast(half8, a), __builtin_bit_cast(half8, b1), acc1, 0, 0, 0);
    }

    // ---- epilogue (C/D: col=lane&15, row=(lane>>4)*4+r) ----
    const int col = lane & 15;
    const int rbase = (lane >> 4) * 4;
    const int h0 = 32 * w + col;
    const int h1 = h0 + 16;
    const float bv0 = bias[h0], bv1 = bias[h1];
    float z0[4], z1[4];
#pragma unroll
    for (int r = 0; r < 4; ++r) {
        z0[r] = fmaxf(acc0[r] + bv0, 0.f);
        z1[r] = fmaxf(acc1[r] + bv1, 0.f);
    }
    if (ow == nullptr) {
#pragma unroll
        for (int r = 0; r < 4; ++r) {
            const size_t nrow = ((size_t)blk * 16 + rbase + r) * DIM;
            out[nrow + h0] = f2h(z0[r]);
            out[nrow + h1] = f2h(z1[r]);
        }
    } else {
        // head: per-thread partial dot, LDS reduce, sigmoid (proven round 8)
        const float w0 = ow[h0], w1 = ow[h1];
        float pr[4];
#pragma unroll
        for (int r = 0; r < 4; ++r) pr[r] = z0[r] * w0 + z1[r] * w1;
        __syncthreads();                    // A16 ds_reads all complete
        float* P = (float*)A16;             // reuse LDS: [wave][node16][col16]
#pragma unroll
        for (int r = 0; r < 4; ++r)
            P[w * 256 + (rbase + r) * 16 + col] = pr[r];
        __syncthreads();
        const int gg = tid >> 4, ii = tid & 15;
        float s = P[gg * 16 + ii] + P[256 + gg * 16 + ii] +
                  P[512 + gg * 16 + ii] + P[768 + gg * 16 + ii];
        s += __shfl_xor(s, 1);
        s += __shfl_xor(s, 2);
        s += __shfl_xor(s, 4);
        s += __shfl_xor(s, 8);
        if (ii == 0)
            head_out[blk * 16 + gg] = 1.0f / (1.0f + __expf(-(s + ob[0])));
    }
}

// ---------------------------------------------------------------- launch ----
extern "C" void kernel_launch(void* const* d_in, const int* in_sizes, int n_in,
                              void* d_out, int out_size, void* d_ws, size_t ws_size,
                              hipStream_t stream) {
    const float* x      = (const float*)d_in[0];
    const int*   ei     = (const int*)d_in[1];
    const int*   et     = (const int*)d_in[2];
    const float* Wrel1  = (const float*)d_in[3];
    const float* Wroot1 = (const float*)d_in[4];
    const float* b1     = (const float*)d_in[5];
    const float* Wrel2  = (const float*)d_in[6];
    const float* Wroot2 = (const float*)d_in[7];
    const float* b2     = (const float*)d_in[8];
    const float* outw   = (const float*)d_in[9];
    const float* outb   = (const float*)d_in[10];
    const int* src = ei;
    const int* dst = ei + NEDGES;

    // workspace layout (~74 MB, 16B-aligned chunks)
    char* ws = (char*)d_ws;
    int*            cnt     = (int*)(ws + 0);                    //  3,200,000
    int*            bsum    = (int*)(ws + 3200064);              //      4,096
    int*            segend  = (int*)(ws + 3204160);              //  3,200,000
    int2*           einfo   = (int2*)(ws + 6404160);             // 12,800,000
    unsigned short* xh      = (unsigned short*)(ws + 19204160);  // 25,600,000
    unsigned short* h1      = (unsigned short*)(ws + 44804160);  // 25,600,000
    unsigned short* Wp1     = (unsigned short*)(ws + 70404160);  //    294,912
    unsigned short* Wp2     = (unsigned short*)(ws + 70699072);  //    294,912
    float*          inv     = (float*)(ws + 70993984);           //  3,200,000
    // end: 74,193,984 B

    hipMemsetAsync(cnt, 0, (size_t)NSEG * 4, stream);
    // grid sized for the LARGER of the two fused jobs (cvt: 3.2M > edges: 1.6M)
    count_cvt<<<(CVT4 + 255) / 256, 256, 0, stream>>>(dst, et, cnt, x, xh);
    scan_pass1<<<NSCAN, 256, 0, stream>>>(cnt, bsum, inv);
    scan_pass2<<<1, 64, 0, stream>>>(bsum);
    scan_pass3<<<NSCAN, 256, 0, stream>>>(cnt, bsum, segend);
    bucket_pack<<<NBUCK + NPACK, 256, 0, stream>>>(src, dst, et, inv, segend, einfo,
                                                   Wrel1, Wroot1, Wrel2, Wroot2,
                                                   Wp1, Wp2);

    fused_layer<<<NNODES / 16, 256, 0, stream>>>(xh, segend, einfo, Wp1, b1, h1,
                                                 nullptr, nullptr, nullptr);
    fused_layer<<<NNODES / 16, 256, 0, stream>>>(h1, segend, einfo, Wp2, b2, h1,
                                                 outw, outb, (float*)d_out);
}